// Round 10
// baseline (55.873 us; speedup 1.0000x reference)
//
#include <hip/hip_runtime.h>
#include <hip/hip_bf16.h>

// ContrastiveLoss: loss = ( sum_{same & sim<1} (1-sim) + sum_{diff & sim>0.5} sim ) / n
// sim = E E^T, n=8192, d=512. int8 MFMA (mfma_i32_16x16x64_i8), exact i32
// accumulation, quant scale 24, dequant 1/576.
// R10: halve the sync-window count. BK 64 -> 128 (i8: 16 KB/operand tile),
// double-buffered LDS (64 KB, 2 blocks/CU = reg-bucket cap anyway), prefetch
// distance 1 (stage kt+1 right after the barrier -> full window in flight),
// 4 windows x {1 vmcnt + 1 barrier + 16 ds_read + 32 MFMA}. 8-chunk swizzle:
// phys chunk = logical ^ (row&7), inverse on global source (rule #21),
// forward on ds_read -> 2-way (free). Rest identical to R9.

typedef int   i32x4 __attribute__((ext_vector_type(4)));
typedef float f32x4 __attribute__((ext_vector_type(4)));

#define N_EMB 8192
#define D_EMB 512
#define BM    128
#define BKB   128                // K-bytes (i8 elems) per window
#define KT    (D_EMB / BKB)      // 4
#define TILES (N_EMB / BM)       // 64
#define NBLK  (TILES * (TILES + 1) / 2)   // 2080
#define MARGIN_F 0.5f
#define QSCALE 24.0f
#define DEQ    (1.0f / (QSCALE * QSCALE))  // 1/576
#define ABYT  (BM * BKB)         // 16384 B per operand tile

__device__ __forceinline__ void gll16(const void* g, void* l) {
    __builtin_amdgcn_global_load_lds(
        (const __attribute__((address_space(1))) void*)g,
        (__attribute__((address_space(3))) void*)l,
        16 /*bytes*/, 0 /*offset*/, 0 /*aux*/);
}

// fp32 -> int8 (scale 24, clamp +-127). 16 floats -> 16 bytes per thread.
__global__ __launch_bounds__(256) void quant_kernel(const float* __restrict__ in,
                                                    int4* __restrict__ out, int n16) {
    int i = blockIdx.x * blockDim.x + threadIdx.x;
    if (i >= n16) return;
    const float4* p = reinterpret_cast<const float4*>(in) + i * 4;
    int4 o;
    int* po = reinterpret_cast<int*>(&o);
#pragma unroll
    for (int j = 0; j < 4; ++j) {
        float4 v = p[j];
        int b0 = (int)rintf(fminf(fmaxf(v.x * QSCALE, -127.f), 127.f));
        int b1 = (int)rintf(fminf(fmaxf(v.y * QSCALE, -127.f), 127.f));
        int b2 = (int)rintf(fminf(fmaxf(v.z * QSCALE, -127.f), 127.f));
        int b3 = (int)rintf(fminf(fmaxf(v.w * QSCALE, -127.f), 127.f));
        po[j] = (b0 & 255) | ((b1 & 255) << 8) | ((b2 & 255) << 16) | ((b3 & 255) << 24);
    }
    out[i] = o;
}

__global__ __launch_bounds__(256) void loss_kernel(const char* __restrict__ E8,
                                                   const int* __restrict__ label,
                                                   float* __restrict__ partials) {
    // T1: XCD-contiguous logical tile index (2080 % 8 == 0)
    const int bid = blockIdx.x;
    const int t = (bid & 7) * (NBLK / 8) + (bid >> 3);

    // triangular decode: t -> (tr, tc), tr <= tc (validated R2/R4/R5/R8/R9)
    int tr = (int)(64.5f - sqrtf(4160.25f - 2.0f * (float)t));
    while ((tr + 1) * TILES - ((tr + 1) * tr) / 2 <= t) ++tr;
    while (tr * TILES - (tr * (tr - 1)) / 2 > t) --tr;
    const int tc = tr + (t - (tr * TILES - (tr * (tr - 1)) / 2));

    __shared__ char  lds[2][2 * ABYT];   // 2 x 32 KB dbuf (A tile then B tile)
    __shared__ float red[4];

    const int tid  = threadIdx.x;
    const int wid  = tid >> 6, lane = tid & 63;
    const int wrow = wid >> 1, wcol = wid & 1;   // 2x2 waves, each 64x64 out
    const int fr   = lane & 15;                  // fragment row(A)/row(B)/col(C)
    const int kq   = lane >> 4;                  // k-16B-chunk 0..3 (per K-half)
    const int row0 = tr * BM, col0 = tc * BM;

    // ---- staging: per operand tile = 128 rows x 128 B = 1024 x 16B slots.
    // Slot s: row r = s>>3, phys chunk = s&7 holds LOGICAL chunk (s&7)^(r&7).
    // Thread covers s = tid + 256j, j=0..3. Low bits: (s&7)=tid&7 and
    // (s>>3)&7 = (tid>>3)&7 for all j -> one swizzled byte-column per thread.
    const int swb = (((tid & 7) ^ ((tid >> 3) & 7)) << 4);
    const int rbase = tid >> 3;                  // row within 32-row j-chunk
    const char* gA[4]; const char* gB[4];
    int dA[4], dB[4];
#pragma unroll
    for (int j = 0; j < 4; ++j) {
        const int r = rbase + 32 * j;
        gA[j] = E8 + (size_t)(row0 + r) * D_EMB + swb;
        gB[j] = E8 + (size_t)(col0 + r) * D_EMB + swb;
        dA[j] = (tid << 4) + (j << 12);
        dB[j] = ABYT + (tid << 4) + (j << 12);
    }

    i32x4 acc[4][4] = {};

    // ds_read phys chunk for K-half h: (4h + kq) ^ (fr&7) = c0 ^ (h<<2),
    // where c0 = kq ^ (fr&7). 16-lane b128 group (same kq): frs 0..7 hit 8
    // distinct chunks, frs 8..15 repeat -> 2-way = free.
    const int c0 = ((kq ^ (fr & 7)) << 4);

    // prologue: stage tiles 0 and 1 (16 glls outstanding)
#pragma unroll
    for (int j = 0; j < 4; ++j) { gll16(gA[j],       lds[0] + dA[j]);
                                  gll16(gB[j],       lds[0] + dB[j]); }
#pragma unroll
    for (int j = 0; j < 4; ++j) { gll16(gA[j] + BKB, lds[1] + dA[j]);
                                  gll16(gB[j] + BKB, lds[1] + dB[j]); }

#pragma unroll 1
    for (int kt = 0; kt < KT; ++kt) {
        // counted wait: tile kt landed. kt==0: tile 1's 8 stay in flight.
        if (kt == 0) {
            asm volatile("s_waitcnt vmcnt(8)" ::: "memory");
        } else {
            asm volatile("s_waitcnt vmcnt(0)" ::: "memory");
        }
        __builtin_amdgcn_s_barrier();   // tile kt visible; buf[(kt+1)&1] reads done

        if (kt + 1 < KT && kt > 0) {    // stage tile kt+1 into the buffer just freed
            const int k1 = (kt + 1) * BKB;
            char* w = lds[(kt + 1) & 1];
#pragma unroll
            for (int j = 0; j < 4; ++j) { gll16(gA[j] + k1, w + dA[j]);
                                          gll16(gB[j] + k1, w + dB[j]); }
        }
        __builtin_amdgcn_sched_barrier(0);   // keep stage-issue ahead of compute

        const char* rd = lds[kt & 1];
        i32x4 a[4][2], b[4][2];
#pragma unroll
        for (int m = 0; m < 4; ++m) {
            const int base = (wrow * 64 + m * 16 + fr) << 7;   // row * 128B
            a[m][0] = *reinterpret_cast<const i32x4*>(&rd[base + c0]);
            a[m][1] = *reinterpret_cast<const i32x4*>(&rd[base + (c0 ^ 64)]);
        }
#pragma unroll
        for (int n = 0; n < 4; ++n) {
            const int base = ABYT + ((wcol * 64 + n * 16 + fr) << 7);
            b[n][0] = *reinterpret_cast<const i32x4*>(&rd[base + c0]);
            b[n][1] = *reinterpret_cast<const i32x4*>(&rd[base + (c0 ^ 64)]);
        }
#pragma unroll
        for (int m = 0; m < 4; ++m)
#pragma unroll
            for (int n = 0; n < 4; ++n) {
                acc[m][n] = __builtin_amdgcn_mfma_i32_16x16x64_i8(a[m][0], b[n][0], acc[m][n], 0, 0, 0);
                acc[m][n] = __builtin_amdgcn_mfma_i32_16x16x64_i8(a[m][1], b[n][1], acc[m][n], 0, 0, 0);
            }
    }

    // ---- epilogue: C/D layout col = lane&15, row = (lane>>4)*4 + reg
    // (dtype-independent, m121-128). Dequant by 1/576.
    float local = 0.f;
    int lj[4];
#pragma unroll
    for (int n = 0; n < 4; ++n) lj[n] = label[col0 + wcol * 64 + n * 16 + fr];
    const int rb = kq << 2;
#pragma unroll
    for (int m = 0; m < 4; ++m) {
#pragma unroll
        for (int r = 0; r < 4; ++r) {
            const int li = label[row0 + wrow * 64 + m * 16 + rb + r];
#pragma unroll
            for (int n = 0; n < 4; ++n) {
                const float s = (float)acc[m][n][r] * DEQ;
                if (li == lj[n]) {
                    if (s < 1.0f) local += 1.0f - s;
                } else if (s > MARGIN_F) {
                    local += s;
                }
            }
        }
    }
    if (tr != tc) local *= 2.0f;   // off-diag tile stands for (i,j) and (j,i)

#pragma unroll
    for (int off = 32; off > 0; off >>= 1) local += __shfl_xor(local, off);
    if (lane == 0) red[wid] = local;
    __syncthreads();
    if (tid == 0) partials[t] = red[0] + red[1] + red[2] + red[3];
}

__global__ __launch_bounds__(256) void reduce_kernel(const float* __restrict__ partials,
                                                     float* __restrict__ out, int nb) {
    float s = 0.f;
    for (int i = threadIdx.x; i < nb; i += 256) s += partials[i];
#pragma unroll
    for (int off = 32; off > 0; off >>= 1) s += __shfl_xor(s, off);
    __shared__ float red[4];
    if ((threadIdx.x & 63) == 0) red[threadIdx.x >> 6] = s;
    __syncthreads();
    if (threadIdx.x == 0) {
        out[0] = (red[0] + red[1] + red[2] + red[3]) * (1.0f / (float)N_EMB);
        out[1] = 0.f;
        out[2] = 0.f;
    }
}

extern "C" void kernel_launch(void* const* d_in, const int* in_sizes, int n_in,
                              void* d_out, int out_size, void* d_ws, size_t ws_size,
                              hipStream_t stream) {
    const float* emb   = (const float*)d_in[0];
    const int*   label = (const int*)d_in[1];
    float*       out   = (float*)d_out;

    char*  E8      = (char*)d_ws;                                   // 4 MB
    float* partial = (float*)((char*)d_ws + (size_t)N_EMB * D_EMB); // 8.3 KB

    const int n16 = N_EMB * D_EMB / 16;
    quant_kernel<<<(n16 + 255) / 256, 256, 0, stream>>>(emb, (int4*)E8, n16);

    loss_kernel<<<NBLK, 256, 0, stream>>>(E8, label, partial);

    reduce_kernel<<<1, 256, 0, stream>>>(partial, out, NBLK);
}

// Round 11
// 46.150 us; speedup vs baseline: 1.2107x; 1.2107x over previous
//
#include <hip/hip_runtime.h>
#include <hip/hip_bf16.h>

// ContrastiveLoss: loss = ( sum_{same & sim<1} (1-sim) + sum_{diff & sim>0.5} sim ) / n
// sim = E E^T, n=8192, d=512. int8 MFMA (mfma_i32_16x16x64_i8), exact i32
// accumulation, quant scale 24, dequant 1/576.
// R11: derived-waits 8-phase schedule (m201-faithful at 128^2/4-wave).
// Phase p (=K-half of 64 i8): { 8 ds_read half p ; 4 gll half p+2 ;
// vmcnt(4) [derived: leaves half p+1's 4 in flight; half p+1 landed] ;
// barrier ; lgkmcnt(0)+sched_barrier ; setprio(1) 16 MFMA setprio(0) ;
// barrier }. LDS = ring-3 of 16 KB half-buffers (48 KB -> 3 blocks/CU).
// Swizzle: phys chunk = logical ^ (row&3), inverse on global source
// (rule #21), forward on ds_read -> 2-way (free). Quant/decode/epilogue/
// T1/triangular grid identical to validated R9.

typedef int   i32x4 __attribute__((ext_vector_type(4)));
typedef float f32x4 __attribute__((ext_vector_type(4)));

#define N_EMB 8192
#define D_EMB 512
#define BM    128
#define HKB   64                 // K-bytes per phase (one i8-MFMA K)
#define NPH   (D_EMB / HKB)      // 8 phases
#define TILES (N_EMB / BM)       // 64
#define NBLK  (TILES * (TILES + 1) / 2)   // 2080
#define MARGIN_F 0.5f
#define QSCALE 24.0f
#define DEQ    (1.0f / (QSCALE * QSCALE))  // 1/576
#define HBYT  (BM * HKB)         // 8192 B per operand half-buffer

__device__ __forceinline__ void gll16(const void* g, void* l) {
    __builtin_amdgcn_global_load_lds(
        (const __attribute__((address_space(1))) void*)g,
        (__attribute__((address_space(3))) void*)l,
        16 /*bytes*/, 0 /*offset*/, 0 /*aux*/);
}

// fp32 -> int8 (scale 24, clamp +-127). 16 floats -> 16 bytes per thread.
__global__ __launch_bounds__(256) void quant_kernel(const float* __restrict__ in,
                                                    int4* __restrict__ out, int n16) {
    int i = blockIdx.x * blockDim.x + threadIdx.x;
    if (i >= n16) return;
    const float4* p = reinterpret_cast<const float4*>(in) + i * 4;
    int4 o;
    int* po = reinterpret_cast<int*>(&o);
#pragma unroll
    for (int j = 0; j < 4; ++j) {
        float4 v = p[j];
        int b0 = (int)rintf(fminf(fmaxf(v.x * QSCALE, -127.f), 127.f));
        int b1 = (int)rintf(fminf(fmaxf(v.y * QSCALE, -127.f), 127.f));
        int b2 = (int)rintf(fminf(fmaxf(v.z * QSCALE, -127.f), 127.f));
        int b3 = (int)rintf(fminf(fmaxf(v.w * QSCALE, -127.f), 127.f));
        po[j] = (b0 & 255) | ((b1 & 255) << 8) | ((b2 & 255) << 16) | ((b3 & 255) << 24);
    }
    out[i] = o;
}

__global__ __launch_bounds__(256) void loss_kernel(const char* __restrict__ E8,
                                                   const int* __restrict__ label,
                                                   float* __restrict__ partials) {
    // T1: XCD-contiguous logical tile index (2080 % 8 == 0)
    const int bid = blockIdx.x;
    const int t = (bid & 7) * (NBLK / 8) + (bid >> 3);

    // triangular decode: t -> (tr, tc), tr <= tc (validated R2..R9)
    int tr = (int)(64.5f - sqrtf(4160.25f - 2.0f * (float)t));
    while ((tr + 1) * TILES - ((tr + 1) * tr) / 2 <= t) ++tr;
    while (tr * TILES - (tr * (tr - 1)) / 2 > t) --tr;
    const int tc = tr + (t - (tr * TILES - (tr * (tr - 1)) / 2));

    // ring-3 of half-buffers: [ring][0]=A half (8 KB), [ring][1]=B half (8 KB)
    __shared__ char  lds[3][2][HBYT];   // 48 KB
    __shared__ float red[4];

    const int tid  = threadIdx.x;
    const int wid  = tid >> 6, lane = tid & 63;
    const int wrow = wid >> 1, wcol = wid & 1;   // 2x2 waves, each 64x64 out
    const int fr   = lane & 15;                  // fragment row(A)/row(B)/col(C)
    const int kq   = lane >> 4;                  // k-16B-chunk 0..3
    const int row0 = tr * BM, col0 = tc * BM;

    // staging map: half-buffer = 128 rows x 64 B = 512 x 16B slots; thread
    // covers slots tid (row r0) and tid+256 (row r1). Phys chunk c of row r
    // holds LOGICAL chunk c ^ (r&3) -> inverse swizzle on the global source;
    // LDS dest stays lane-linear. Swizzle bits identical for both slots.
    const int sw = (((tid & 3) ^ ((tid >> 2) & 3)) << 4);
    const int r0 = tid >> 2, r1 = 64 + (tid >> 2);
    const char* gA0 = E8 + (size_t)(row0 + r0) * D_EMB + sw;
    const char* gA1 = E8 + (size_t)(row0 + r1) * D_EMB + sw;
    const char* gB0 = E8 + (size_t)(col0 + r0) * D_EMB + sw;
    const char* gB1 = E8 + (size_t)(col0 + r1) * D_EMB + sw;
    const int d0 = tid << 4;           // byte offset of slot tid
    const int d1 = (tid + 256) << 4;   // byte offset of slot tid+256

    i32x4 acc[4][4] = {};

    // ds_read phys chunk: kq ^ (row&3), row&3 == fr&3 for all fragment rows.
    const int psw = ((kq ^ (fr & 3)) << 4);

    // prologue: stage halves 0 (ring 0) and 1 (ring 1); wait half 0 landed.
    gll16(gA0,       &lds[0][0][d0]); gll16(gA1,       &lds[0][0][d1]);
    gll16(gB0,       &lds[0][1][d0]); gll16(gB1,       &lds[0][1][d1]);
    gll16(gA0 + HKB, &lds[1][0][d0]); gll16(gA1 + HKB, &lds[1][0][d1]);
    gll16(gB0 + HKB, &lds[1][1][d0]); gll16(gB1 + HKB, &lds[1][1][d1]);
    asm volatile("s_waitcnt vmcnt(4)" ::: "memory");
    __builtin_amdgcn_s_barrier();

#pragma unroll
    for (int p = 0; p < NPH; ++p) {
        const int rg = p % 3;
        // step 1: ds_read this phase's fragments (in flight across barrier)
        i32x4 a[4], b[4];
#pragma unroll
        for (int m = 0; m < 4; ++m)
            a[m] = *reinterpret_cast<const i32x4*>(
                &lds[rg][0][((wrow * 64 + m * 16 + fr) << 6) + psw]);
#pragma unroll
        for (int n = 0; n < 4; ++n)
            b[n] = *reinterpret_cast<const i32x4*>(
                &lds[rg][1][((wcol * 64 + n * 16 + fr) << 6) + psw]);
        // step 2: stage half p+2 into ring (p+2)%3 (its last reader was
        // phase p-1, separated by two barriers)
        if (p + 2 < NPH) {
            const int rg2 = (p + 2) % 3;
            const int ko  = (p + 2) * HKB;
            gll16(gA0 + ko, &lds[rg2][0][d0]); gll16(gA1 + ko, &lds[rg2][0][d1]);
            gll16(gB0 + ko, &lds[rg2][1][d0]); gll16(gB1 + ko, &lds[rg2][1][d1]);
        }
        // step 3: derived wait — half p+1's 4 glls land, p+2's stay in flight
        if (p < NPH - 2) {
            asm volatile("s_waitcnt vmcnt(4)" ::: "memory");
        } else if (p == NPH - 2) {
            asm volatile("s_waitcnt vmcnt(0)" ::: "memory");
        }
        __builtin_amdgcn_s_barrier();
        asm volatile("s_waitcnt lgkmcnt(0)" ::: "memory");
        __builtin_amdgcn_sched_barrier(0);
        __builtin_amdgcn_s_setprio(1);
#pragma unroll
        for (int m = 0; m < 4; ++m)
#pragma unroll
            for (int n = 0; n < 4; ++n)
                acc[m][n] = __builtin_amdgcn_mfma_i32_16x16x64_i8(a[m], b[n], acc[m][n], 0, 0, 0);
        __builtin_amdgcn_s_setprio(0);
        __builtin_amdgcn_s_barrier();
    }

    // ---- epilogue: C/D layout col = lane&15, row = (lane>>4)*4 + reg
    // (dtype-independent, m121-128). Dequant by 1/576.
    float local = 0.f;
    int lj[4];
#pragma unroll
    for (int n = 0; n < 4; ++n) lj[n] = label[col0 + wcol * 64 + n * 16 + fr];
    const int rb = kq << 2;
#pragma unroll
    for (int m = 0; m < 4; ++m) {
#pragma unroll
        for (int r = 0; r < 4; ++r) {
            const int li = label[row0 + wrow * 64 + m * 16 + rb + r];
#pragma unroll
            for (int n = 0; n < 4; ++n) {
                const float s = (float)acc[m][n][r] * DEQ;
                if (li == lj[n]) {
                    if (s < 1.0f) local += 1.0f - s;
                } else if (s > MARGIN_F) {
                    local += s;
                }
            }
        }
    }
    if (tr != tc) local *= 2.0f;   // off-diag tile stands for (i,j) and (j,i)

#pragma unroll
    for (int off = 32; off > 0; off >>= 1) local += __shfl_xor(local, off);
    if (lane == 0) red[wid] = local;
    __syncthreads();
    if (tid == 0) partials[t] = red[0] + red[1] + red[2] + red[3];
}

__global__ __launch_bounds__(256) void reduce_kernel(const float* __restrict__ partials,
                                                     float* __restrict__ out, int nb) {
    float s = 0.f;
    for (int i = threadIdx.x; i < nb; i += 256) s += partials[i];
#pragma unroll
    for (int off = 32; off > 0; off >>= 1) s += __shfl_xor(s, off);
    __shared__ float red[4];
    if ((threadIdx.x & 63) == 0) red[threadIdx.x >> 6] = s;
    __syncthreads();
    if (threadIdx.x == 0) {
        out[0] = (red[0] + red[1] + red[2] + red[3]) * (1.0f / (float)N_EMB);
        out[1] = 0.f;
        out[2] = 0.f;
    }
}

extern "C" void kernel_launch(void* const* d_in, const int* in_sizes, int n_in,
                              void* d_out, int out_size, void* d_ws, size_t ws_size,
                              hipStream_t stream) {
    const float* emb   = (const float*)d_in[0];
    const int*   label = (const int*)d_in[1];
    float*       out   = (float*)d_out;

    char*  E8      = (char*)d_ws;                                   // 4 MB
    float* partial = (float*)((char*)d_ws + (size_t)N_EMB * D_EMB); // 8.3 KB

    const int n16 = N_EMB * D_EMB / 16;
    quant_kernel<<<(n16 + 255) / 256, 256, 0, stream>>>(emb, (int4*)E8, n16);

    loss_kernel<<<NBLK, 256, 0, stream>>>(E8, label, partial);

    reduce_kernel<<<1, 256, 0, stream>>>(partial, out, NBLK);
}